// Round 13
// baseline (661.432 us; speedup 1.0000x reference)
//
#include <hip/hip_runtime.h>

// HBMA fused: full-search block matching (16x16 blocks, +/-4 search) + predicted
// frame gather. N=8, C=3, H=W=1024.
//
// R13 = R8 compute core + vertical double-buffered staging (SPW=4, 2048 wgs),
// rebuilt for register discipline after R12's spill (VGPR 128 + 109MB scratch):
//  * staging descriptors (9 ptrs + 9 row idx + x-valid bitmask) precomputed
//    ONCE per thread; per-strip stage is ~8 VALU/chunk (add Y-offset, y-test,
//    cndmask zsrc) -- no div/mod chains in the loop.
//  * 16-lane column reduce via DPP row_ror (VALU pipe) instead of __shfl_xor
//    (ds_swizzle, LDS pipe): -108 LDS-pipe ops/wave.
//  * register-only argmin (R10's, absmax 0): no costL LDS traffic.
//  * per phase: stage(next buf) -> compute(cur buf) -> s_waitcnt vmcnt(12)
//    lgkmcnt(0) -> s_barrier. vmcnt(12): the 12 newest vmem ops are this
//    lane's gather stores; the 9 stage loads are older => complete, while
//    stores may stay in flight. Stage latency hides under ~3.5us compute.
// Tie-break: in-lane scan ascending disp index with strict <, cross-lane min
// with lowest-index-wins == jax scan semantics. OOB ref chunks load a zeroed
// 16B block (MV region of d_out, zeroed by init_kernel each launch).

namespace {
constexpr int BLKi  = 16;
constexpr int NSDi  = 4;
constexpr int ND    = 9;
constexpr int Nn    = 8;
constexpr int Cc    = 3;
constexpr int Hh    = 1024;
constexpr int Ww    = 1024;
constexpr int BHn   = 64;
constexpr int STRIPW = 64;                    // 4 blocks per wg, side by side
constexpr int SW    = 72;                     // strip width  (64 + 8)
constexpr int SH    = 24;                     // strip height (16 + 8)
constexpr int STRIP_FLOATS = Cc * SH * SW;    // 5184
constexpr int STRIP_CHUNKS = STRIP_FLOATS/4;  // 1296 (18/row: chunks never straddle)
constexpr int TGT_FLOATS   = Cc * BLKi * STRIPW; // 3072
constexpr int TOT_CHUNKS   = STRIP_CHUNKS + TGT_FLOATS / 4; // 2064
constexpr int ITERS        = 9;               // 9*256 = 2304 >= 2064
constexpr int BUF_FLOATS   = ITERS * 256 * 4; // 9216 floats per buffer
constexpr int MV_SIZE = Nn * 2 * BHn * BHn;   // 65536
constexpr int SPW     = 4;                    // strips per wg (vertical)
constexpr int NWG     = Nn * (BHn / SPW) * (Ww / STRIPW); // 2048
static_assert(TOT_CHUNKS <= ITERS * 256, "chunk budget");
}

typedef const __attribute__((address_space(1))) void* gas_ptr;
typedef __attribute__((address_space(3))) void*       las_ptr;

__global__ void init_kernel(float* __restrict__ out) {
    int i = blockIdx.x * 256 + threadIdx.x;
    if (i < MV_SIZE) out[i] = 0.0f;   // MV output = zeros; doubles as zero-source
}

// acc += row_ror<CTRL>(acc): DPP rotate within the 16-lane row, VALU pipe only.
template<int CTRL>
__device__ __forceinline__ float dpp_ror_add(float x) {
    int r = __builtin_amdgcn_update_dpp(__float_as_int(x), __float_as_int(x),
                                        CTRL, 0xf, 0xf, false);
    return x + __int_as_float(r);
}

__global__ __launch_bounds__(256, 2) void hbma_kernel(
        const float* __restrict__ ref,
        const float* __restrict__ tgt,
        float* __restrict__ pred,
        const float* __restrict__ zsrc) {
    __shared__ float ldsA[2 * BUF_FLOATS];     // double-buffered strip

    const int tid  = (int)threadIdx.x;
    const int wid  = tid >> 6;
    const int lane = tid & 63;
    const int wg   = (int)blockIdx.x;          // 0..2047
    const int n    = wg >> 8;                  // 256 wg per image
    const int rem  = wg & 255;
    const int ygrp = rem >> 4;                 // 0..15 (4 block-rows each)
    const int X0   = (rem & 15) * STRIPW;
    const float* refn  = ref  + (size_t)n * Cc * Hh * Ww;
    const float* tgtn  = tgt  + (size_t)n * Cc * Hh * Ww;
    float*       predn = pred + (size_t)n * Cc * Hh * Ww;

    const int col  = lane & 15;
    const int g    = lane >> 4;
    const int d0   = g * 3;                    // 0,3,6 (9 = idle group, harmless)
    const int colS = (wid << 4) + col;

    // ---- precompute staging descriptors (once) ----
    // chunk ck = i*256+tid -> qb[i] = base ptr without the Y0 row term,
    // rl[i] = row offset relative to Y0, xmask bit i = x-in-bounds & active.
    const float* qb[ITERS];
    int rl[ITERS];
    unsigned xmask = 0;
    #pragma unroll
    for (int i = 0; i < ITERS; ++i) {
        const int ck = i * 256 + tid;
        const float* p; int rlow; bool xok;
        if (ck < STRIP_CHUNKS) {
            const int c    = ck / 432;
            const int rm   = ck - c * 432;
            const int r    = rm / 18;
            const int colc = (rm - r * 18) * 4;
            const int gx   = X0 - NSDi + colc;         // 4-aligned: all-in/all-out
            rlow = r - NSDi;                           // -4..19
            xok  = ((unsigned)gx < (unsigned)Ww);
            p    = refn + ((c << 20) + (rlow << 10) + gx);
        } else {
            const int tk   = ck - STRIP_CHUNKS;        // may exceed 768 for tail
            const int c    = tk >> 8;
            const int rm2  = tk & 255;
            const int y    = rm2 >> 4;
            const int colc = (rm2 & 15) * 4;
            rlow = y;                                  // 0..15: y-check always true
            xok  = (ck < TOT_CHUNKS);                  // tail lanes -> zsrc
            p    = tgtn + ((c << 20) + (y << 10) + X0 + colc);
        }
        qb[i] = p; rl[i] = rlow;
        xmask |= (xok ? 1u : 0u) << i;
    }

    // ---- staging: 9 global_load_lds into buf for strip at Y0 ----
    auto STAGE = [&](float* buf, int Y0) {
        const int yoff = Y0 << 10;                     // floats
        #pragma unroll
        for (int i = 0; i < ITERS; ++i) {
            const int gy   = Y0 + rl[i];
            const bool ok  = ((xmask >> i) & 1u) && ((unsigned)gy < (unsigned)Hh);
            const float* src = ok ? (qb[i] + yoff) : zsrc;
            __builtin_amdgcn_global_load_lds((gas_ptr)src,
                    (las_ptr)(buf + i * 1024 + (tid & 192) * 4), 16, 0, 0);
        }
        __builtin_amdgcn_sched_barrier(0);             // pin stage before compute
    };

    // ---- compute one strip from buf (R8 math; DPP reduce; reg argmin) ----
    auto COMP = [&](const float* buf, int Y0) {
        const float* __restrict__ ldsT = buf + STRIP_FLOATS;

        float acc[ND][3];
        #pragma unroll
        for (int j = 0; j < ND; ++j) {
            acc[j][0] = 0.0f; acc[j][1] = 0.0f; acc[j][2] = 0.0f;
        }

        #pragma unroll 1
        for (int c = 0; c < Cc; ++c) {
            float T[BLKi];
            #pragma unroll
            for (int y = 0; y < BLKi; ++y)
                T[y] = ldsT[(c * BLKi + y) * STRIPW + colS];

            #pragma unroll
            for (int r = 0; r < SH; ++r) {
                const float* rp = buf + (c * SH + r) * SW + colS + d0;
                const float rv0 = rp[0], rv1 = rp[1], rv2 = rp[2];
                #pragma unroll
                for (int j = 0; j < ND; ++j) {
                    const int y = r - j;               // compile-time after unroll
                    if (y >= 0 && y < BLKi) {
                        const float tv = T[y];
                        acc[j][0] += fabsf(rv0 - tv);
                        acc[j][1] += fabsf(rv1 - tv);
                        acc[j][2] += fabsf(rv2 - tv);
                    }
                }
            }
        }

        // 16-lane column reduce on the VALU pipe (DPP row rotations)
        #pragma unroll
        for (int j = 0; j < ND; ++j) {
            #pragma unroll
            for (int dd = 0; dd < 3; ++dd) {
                float v = acc[j][dd];
                v = dpp_ror_add<0x128>(v);             // row_ror:8
                v = dpp_ror_add<0x124>(v);             // row_ror:4
                v = dpp_ror_add<0x122>(v);             // row_ror:2
                v = dpp_ror_add<0x121>(v);             // row_ror:1
                acc[j][dd] = v;
            }
        }

        // register-only argmin: in-lane ascending index, strict <
        float bc = 3.4e38f;
        int   bj = 0x7fffffff;
        if (g < 3) {
            #pragma unroll
            for (int j = 0; j < ND; ++j)
                #pragma unroll
                for (int dd = 0; dd < 3; ++dd) {
                    const float cst = acc[j][dd];
                    if (cst < bc) { bc = cst; bj = j * ND + d0 + dd; }
                }
        }
        #pragma unroll
        for (int m = 1; m <= 32; m <<= 1) {
            const float oc = __shfl_xor(bc, m, 64);
            const int   oi = __shfl_xor(bj, m, 64);
            if (oc < bc || (oc == bc && oi < bj)) { bc = oc; bj = oi; }
        }
        const int by = bj / ND;                        // dy + 4
        const int bx = bj % ND;                        // dx + 4

        // gather predicted block from LDS strip (already zero-padded)
        #pragma unroll 1
        for (int c = 0; c < Cc; ++c) {
            #pragma unroll
            for (int yy = 0; yy < 4; ++yy) {
                const int y = (g << 2) + yy;
                const float v = buf[(c * SH + y + by) * SW + colS + bx];
                predn[(c << 20) + ((Y0 + y) << 10) + X0 + colS] = v;
            }
        }
    };

    float* bufA = ldsA;
    float* bufB = ldsA + BUF_FLOATS;
    const int Ybase = ygrp * (SPW * BLKi);

    // prologue: stage strip 0
    STAGE(bufA, Ybase);
    asm volatile("s_waitcnt vmcnt(0)" ::: "memory");
    __builtin_amdgcn_s_barrier();
    __builtin_amdgcn_sched_barrier(0);

    #pragma unroll 1
    for (int base = 0; base < SPW; base += 2) {
        if (base + 1 < SPW) STAGE(bufB, Ybase + (base + 1) * BLKi);
        COMP(bufA, Ybase + base * BLKi);
        asm volatile("s_waitcnt vmcnt(12) lgkmcnt(0)" ::: "memory");
        __builtin_amdgcn_s_barrier();
        __builtin_amdgcn_sched_barrier(0);

        if (base + 2 < SPW) STAGE(bufA, Ybase + (base + 2) * BLKi);
        COMP(bufB, Ybase + (base + 1) * BLKi);
        asm volatile("s_waitcnt vmcnt(12) lgkmcnt(0)" ::: "memory");
        __builtin_amdgcn_s_barrier();
        __builtin_amdgcn_sched_barrier(0);
    }
}

extern "C" void kernel_launch(void* const* d_in, const int* in_sizes, int n_in,
                              void* d_out, int out_size, void* d_ws, size_t ws_size,
                              hipStream_t stream) {
    const float* ref = (const float*)d_in[0];
    const float* tgt = (const float*)d_in[1];
    float* out = (float*)d_out;

    init_kernel<<<dim3((MV_SIZE + 255) / 256), dim3(256), 0, stream>>>(out);

    // zsrc = MV region (zeroed by init_kernel on this stream, never written after)
    hbma_kernel<<<dim3(NWG), dim3(256), 0, stream>>>(ref, tgt, out + MV_SIZE, out);
}

// Round 14
// 213.256 us; speedup vs baseline: 3.1016x; 3.1016x over previous
//
#include <hip/hip_runtime.h>

// R14: ABLATION ROUND. Two heavy kernels per launch:
//  1) hbma_abl  = R8 with the global->LDS staging REMOVED (reads uninit LDS,
//     same SAD/reduce/argmin/gather instruction stream, writes garbage pred).
//     Measures the pure compute-pipeline cost C with "free" staging.
//  2) hbma_kernel = EXACT R8 (230us baseline) runs LAST, overwriting every
//     output element -> final output correct (absmax 0 preserved).
// Readout: C = dur_us - 230 - init(~3us). Branch next round on C.
// (Counter table will show only the slower K_full replays - expected.)

namespace {
constexpr int BLKi  = 16;
constexpr int NSDi  = 4;
constexpr int ND    = 9;
constexpr int NDISP = 81;
constexpr int Nn    = 8;
constexpr int Cc    = 3;
constexpr int Hh    = 1024;
constexpr int Ww    = 1024;
constexpr int BHn   = 64;
constexpr int STRIPW = 64;
constexpr int SW    = 72;
constexpr int SH    = 24;
constexpr int STRIP_FLOATS = Cc * SH * SW;    // 5184
constexpr int STRIP_CHUNKS = STRIP_FLOATS/4;  // 1296
constexpr int TGT_FLOATS   = Cc * BLKi * STRIPW; // 3072
constexpr int TOT_CHUNKS   = STRIP_CHUNKS + TGT_FLOATS / 4; // 2064
constexpr int ITERS        = 9;
constexpr int LDSF         = ITERS * 256 * 4; // 9216 floats
constexpr int MV_SIZE = Nn * 2 * BHn * BHn;   // 65536
constexpr int NWG     = Nn * BHn * (Ww / STRIPW); // 8192
}

typedef const __attribute__((address_space(1))) void* gas_ptr;
typedef __attribute__((address_space(3))) void*       las_ptr;

__global__ void init_kernel(float* __restrict__ out) {
    int i = blockIdx.x * 256 + threadIdx.x;
    if (i < MV_SIZE) out[i] = 0.0f;
}

// ---------------- ablation kernel: R8 minus staging ----------------
__global__ __launch_bounds__(256, 2) void hbma_abl(
        const float* __restrict__ ref,
        const float* __restrict__ tgt,
        float* __restrict__ pred,
        const float* __restrict__ zsrc) {
    __shared__ float ldsA[LDSF];
    __shared__ float costL[4][NDISP];

    const int tid  = (int)threadIdx.x;
    const int wid  = tid >> 6;
    const int lane = tid & 63;
    const int w    = (int)blockIdx.x;
    const int n    = w >> 10;
    const int rem  = w & 1023;
    const int Y0   = (rem >> 4) * BLKi;
    const int X0   = (rem & 15) * STRIPW;
    float* predn = pred + (size_t)n * Cc * Hh * Ww;

    // (staging deleted -- LDS holds garbage; instruction stream below identical)
    __syncthreads();

    const int col  = lane & 15;
    const int g    = lane >> 4;
    const int d0   = g * 3;
    const int colS = (wid << 4) + col;
    const float* __restrict__ ldsT = ldsA + STRIP_FLOATS;

    float acc[ND][3];
    #pragma unroll
    for (int j = 0; j < ND; ++j) {
        acc[j][0] = 0.0f; acc[j][1] = 0.0f; acc[j][2] = 0.0f;
    }

    #pragma unroll 1
    for (int c = 0; c < Cc; ++c) {
        float T[BLKi];
        #pragma unroll
        for (int y = 0; y < BLKi; ++y)
            T[y] = ldsT[(c * BLKi + y) * STRIPW + colS];

        #pragma unroll
        for (int r = 0; r < SH; ++r) {
            const float* rp = ldsA + (c * SH + r) * SW + colS + d0;
            const float rv0 = rp[0], rv1 = rp[1], rv2 = rp[2];
            #pragma unroll
            for (int j = 0; j < ND; ++j) {
                const int y = r - j;
                if (y >= 0 && y < BLKi) {
                    const float tv = T[y];
                    acc[j][0] += fabsf(rv0 - tv);
                    acc[j][1] += fabsf(rv1 - tv);
                    acc[j][2] += fabsf(rv2 - tv);
                }
            }
        }
    }

    #pragma unroll
    for (int m = 1; m <= 8; m <<= 1)
        #pragma unroll
        for (int j = 0; j < ND; ++j) {
            acc[j][0] += __shfl_xor(acc[j][0], m, 64);
            acc[j][1] += __shfl_xor(acc[j][1], m, 64);
            acc[j][2] += __shfl_xor(acc[j][2], m, 64);
        }

    #pragma unroll
    for (int jj = 0; jj < ND; ++jj) {
        if (g < 3 && col == jj) {
            costL[wid][jj * ND + d0 + 0] = acc[jj][0];
            costL[wid][jj * ND + d0 + 1] = acc[jj][1];
            costL[wid][jj * ND + d0 + 2] = acc[jj][2];
        }
    }
    asm volatile("s_waitcnt lgkmcnt(0)" ::: "memory");

    float bc = costL[wid][lane];
    int   bj = lane;
    if (lane < NDISP - 64) {
        float c2 = costL[wid][lane + 64];
        if (c2 < bc) { bc = c2; bj = lane + 64; }
    }
    #pragma unroll
    for (int m = 1; m <= 32; m <<= 1) {
        float oc = __shfl_xor(bc, m, 64);
        int   oi = __shfl_xor(bj, m, 64);
        if (oc < bc || (oc == bc && oi < bj)) { bc = oc; bj = oi; }
    }
    const int by = bj / ND;
    const int bx = bj % ND;

    #pragma unroll 1
    for (int c = 0; c < Cc; ++c) {
        #pragma unroll
        for (int yy = 0; yy < 4; ++yy) {
            const int y = (g << 2) + yy;
            const float v = ldsA[(c * SH + y + by) * SW + colS + bx];
            predn[(c << 20) + ((Y0 + y) << 10) + X0 + colS] = v;
        }
    }
}

// ---------------- exact R8 kernel (runs last; produces correct output) ------
__global__ __launch_bounds__(256, 2) void hbma_kernel(
        const float* __restrict__ ref,
        const float* __restrict__ tgt,
        float* __restrict__ pred,
        const float* __restrict__ zsrc) {
    __shared__ float ldsA[LDSF];
    __shared__ float costL[4][NDISP];

    const int tid  = (int)threadIdx.x;
    const int wid  = tid >> 6;
    const int lane = tid & 63;
    const int w    = (int)blockIdx.x;
    const int n    = w >> 10;
    const int rem  = w & 1023;
    const int Y0   = (rem >> 4) * BLKi;
    const int X0   = (rem & 15) * STRIPW;
    const float* refn  = ref  + (size_t)n * Cc * Hh * Ww;
    const float* tgtn  = tgt  + (size_t)n * Cc * Hh * Ww;
    float*       predn = pred + (size_t)n * Cc * Hh * Ww;

    #pragma unroll
    for (int i = 0; i < ITERS; ++i) {
        const int ck = i * 256 + tid;
        if (ck < TOT_CHUNKS) {
            const float* src;
            if (ck < STRIP_CHUNKS) {
                const int c    = ck / (SH * SW / 4);
                const int rm   = ck - c * (SH * SW / 4);
                const int r    = rm / (SW / 4);
                const int colc = (rm - r * (SW / 4)) * 4;
                const int gy   = Y0 - NSDi + r;
                const int gx   = X0 - NSDi + colc;
                const bool ok  = ((unsigned)gy < (unsigned)Hh) &&
                                 ((unsigned)gx < (unsigned)Ww);
                src = ok ? (refn + (c << 20) + (gy << 10) + gx) : zsrc;
            } else {
                const int tk   = ck - STRIP_CHUNKS;
                const int c    = tk >> 8;
                const int rm2  = tk & 255;
                const int y    = rm2 >> 4;
                const int colc = (rm2 & 15) * 4;
                src = tgtn + (c << 20) + ((Y0 + y) << 10) + X0 + colc;
            }
            __builtin_amdgcn_global_load_lds((gas_ptr)src,
                    (las_ptr)(ldsA + i * 1024 + (tid & 192) * 4), 16, 0, 0);
        }
    }
    __syncthreads();

    const int col  = lane & 15;
    const int g    = lane >> 4;
    const int d0   = g * 3;
    const int colS = (wid << 4) + col;
    const float* __restrict__ ldsT = ldsA + STRIP_FLOATS;

    float acc[ND][3];
    #pragma unroll
    for (int j = 0; j < ND; ++j) {
        acc[j][0] = 0.0f; acc[j][1] = 0.0f; acc[j][2] = 0.0f;
    }

    #pragma unroll 1
    for (int c = 0; c < Cc; ++c) {
        float T[BLKi];
        #pragma unroll
        for (int y = 0; y < BLKi; ++y)
            T[y] = ldsT[(c * BLKi + y) * STRIPW + colS];

        #pragma unroll
        for (int r = 0; r < SH; ++r) {
            const float* rp = ldsA + (c * SH + r) * SW + colS + d0;
            const float rv0 = rp[0], rv1 = rp[1], rv2 = rp[2];
            #pragma unroll
            for (int j = 0; j < ND; ++j) {
                const int y = r - j;
                if (y >= 0 && y < BLKi) {
                    const float tv = T[y];
                    acc[j][0] += fabsf(rv0 - tv);
                    acc[j][1] += fabsf(rv1 - tv);
                    acc[j][2] += fabsf(rv2 - tv);
                }
            }
        }
    }

    #pragma unroll
    for (int m = 1; m <= 8; m <<= 1)
        #pragma unroll
        for (int j = 0; j < ND; ++j) {
            acc[j][0] += __shfl_xor(acc[j][0], m, 64);
            acc[j][1] += __shfl_xor(acc[j][1], m, 64);
            acc[j][2] += __shfl_xor(acc[j][2], m, 64);
        }

    #pragma unroll
    for (int jj = 0; jj < ND; ++jj) {
        if (g < 3 && col == jj) {
            costL[wid][jj * ND + d0 + 0] = acc[jj][0];
            costL[wid][jj * ND + d0 + 1] = acc[jj][1];
            costL[wid][jj * ND + d0 + 2] = acc[jj][2];
        }
    }
    asm volatile("s_waitcnt lgkmcnt(0)" ::: "memory");

    float bc = costL[wid][lane];
    int   bj = lane;
    if (lane < NDISP - 64) {
        float c2 = costL[wid][lane + 64];
        if (c2 < bc) { bc = c2; bj = lane + 64; }
    }
    #pragma unroll
    for (int m = 1; m <= 32; m <<= 1) {
        float oc = __shfl_xor(bc, m, 64);
        int   oi = __shfl_xor(bj, m, 64);
        if (oc < bc || (oc == bc && oi < bj)) { bc = oc; bj = oi; }
    }
    const int by = bj / ND;
    const int bx = bj % ND;

    #pragma unroll 1
    for (int c = 0; c < Cc; ++c) {
        #pragma unroll
        for (int yy = 0; yy < 4; ++yy) {
            const int y = (g << 2) + yy;
            const float v = ldsA[(c * SH + y + by) * SW + colS + bx];
            predn[(c << 20) + ((Y0 + y) << 10) + X0 + colS] = v;
        }
    }
}

extern "C" void kernel_launch(void* const* d_in, const int* in_sizes, int n_in,
                              void* d_out, int out_size, void* d_ws, size_t ws_size,
                              hipStream_t stream) {
    const float* ref = (const float*)d_in[0];
    const float* tgt = (const float*)d_in[1];
    float* out = (float*)d_out;

    init_kernel<<<dim3((MV_SIZE + 255) / 256), dim3(256), 0, stream>>>(out);

    // ablation first (garbage output)...
    hbma_abl<<<dim3(NWG), dim3(256), 0, stream>>>(ref, tgt, out + MV_SIZE, out);
    // ...then exact R8, which overwrites ALL outputs -> correct final state.
    hbma_kernel<<<dim3(NWG), dim3(256), 0, stream>>>(ref, tgt, out + MV_SIZE, out);
}